// Round 6
// baseline (208.041 us; speedup 1.0000x reference)
//
#include <hip/hip_runtime.h>
#include <math.h>

#define BATCH 4
#define SEQ   2048
#define DM    1024
#define NTOK  (BATCH * SEQ)   // 8192

typedef __attribute__((ext_vector_type(8))) short bf16x8;
typedef __attribute__((ext_vector_type(4))) float f32x4;
typedef unsigned short u16;
struct alignas(8) us4 { u16 x, y, z, w; };

__device__ __forceinline__ u16 f2bf(float f) {
    union { float f; unsigned u; } v; v.f = f;
    unsigned r = v.u + 0x7fffu + ((v.u >> 16) & 1u);   // round-to-nearest-even
    return (u16)(r >> 16);
}

__device__ __forceinline__ void gload_lds16(const void* g, void* l) {
    __builtin_amdgcn_global_load_lds(
        (const __attribute__((address_space(1))) unsigned int*)g,
        (__attribute__((address_space(3))) unsigned int*)l, 16, 0, 0);
}

// Stage a 128-row x 32-k bf16 tile from row-major global (ld elems) into a
// linear LDS tile [128][32]. 4 waves x 2 issues x 64 lanes x 16B = 8192 B.
// LDS dest is wave-uniform base + lane*16 (HW rule); global src is per-lane.
__device__ __forceinline__ void stage_tile(
    const u16* __restrict__ G, int ld, int row0, int kt,
    u16* lds, int wid, int lane)
{
    #pragma unroll
    for (int j = 0; j < 2; ++j) {
        const int off  = wid * 2048 + j * 1024;     // bytes, wave-uniform
        const int loff = off + lane * 16;           // this lane's dest byte
        const int row  = loff >> 6;                 // 64 B per row
        const int ke   = (loff & 63) >> 1;          // k-element offset
        gload_lds16(G + (size_t)(row0 + row) * ld + kt + ke, (char*)lds + off);
    }
}

// Per wave: 4x4 fragments of 16x16x32 over a 64x64 sub-tile.
// A-frag lane map: A[lane&15][(lane>>4)*8 + j]; B operand loaded identically
// from the [N][K] tile gives NT semantics. C/D: col=lane&15, row=(lane>>4)*4+r.
__device__ __forceinline__ void frag_mma(
    const u16* As, const u16* Bs, int wr, int wc, int lane, f32x4 acc[4][4])
{
    const int lrow = lane & 15, lk = (lane >> 4) * 8;
    bf16x8 a[4], b[4];
    #pragma unroll
    for (int i = 0; i < 4; ++i)
        a[i] = *(const bf16x8*)(As + (wr * 64 + i * 16 + lrow) * 32 + lk);
    #pragma unroll
    for (int i = 0; i < 4; ++i)
        b[i] = *(const bf16x8*)(Bs + (wc * 64 + i * 16 + lrow) * 32 + lk);
    #pragma unroll
    for (int i = 0; i < 4; ++i)
        #pragma unroll
        for (int j = 0; j < 4; ++j)
            acc[i][j] = __builtin_amdgcn_mfma_f32_16x16x32_bf16(
                a[i], b[j], acc[i][j], 0, 0, 0);
}

// ---------------------------------------------------------------------------
// f32 -> bf16 convert, float4 in / us4 out
// ---------------------------------------------------------------------------
__global__ __launch_bounds__(256) void conv_bf16(
    const float* __restrict__ in, u16* __restrict__ out, int n4)
{
    for (int i = blockIdx.x * 256 + threadIdx.x; i < n4; i += gridDim.x * 256) {
        float4 f = ((const float4*)in)[i];
        us4 p{f2bf(f.x), f2bf(f.y), f2bf(f.z), f2bf(f.w)};
        ((us4*)out)[i] = p;
    }
}

// 3 weight matrices in one launch (z selects), saves 2 launch overheads
__global__ __launch_bounds__(256) void conv_bf16_w3(
    const float* __restrict__ w0, const float* __restrict__ w1,
    const float* __restrict__ w2,
    u16* __restrict__ o0, u16* __restrict__ o1, u16* __restrict__ o2)
{
    const int z = blockIdx.z;
    const float* in = (z == 0) ? w0 : (z == 1) ? w1 : w2;
    u16* out = (z == 0) ? o0 : (z == 1) ? o1 : o2;
    const int n4 = DM * DM / 4;
    for (int i = blockIdx.x * 256 + threadIdx.x; i < n4; i += gridDim.x * 256) {
        float4 f = ((const float4*)in)[i];
        us4 p{f2bf(f.x), f2bf(f.y), f2bf(f.z), f2bf(f.w)};
        ((us4*)out)[i] = p;
    }
}

// ---------------------------------------------------------------------------
// QKV projection: NT GEMM  out[m][n] = sum_k x[m][k] W[n][k] + b[n]
// Double-buffered: prefetch tile t+1 issued BEFORE MFMA of tile t; the
// single __syncthreads() (vmcnt0+lgkmcnt0 drain) per K-step lands after
// compute, so load latency hides under MFMA+ds_read.
// z=0 -> q bf16 [NTOK][DM], z=1 -> k bf16, z=2 -> vT bf16 [DM][NTOK]
// ---------------------------------------------------------------------------
__global__ __launch_bounds__(256) void qkv_mfma(
    const u16* __restrict__ xb,
    const u16* __restrict__ wqb, const float* __restrict__ bq,
    const u16* __restrict__ wkb, const float* __restrict__ bk,
    const u16* __restrict__ wvb, const float* __restrict__ bv,
    u16* __restrict__ qb, u16* __restrict__ kb, u16* __restrict__ vT)
{
    __shared__ u16 As[2][128 * 32], Bs[2][128 * 32];
    const int z = blockIdx.z;
    const u16* W = (z == 0) ? wqb : (z == 1) ? wkb : wvb;
    const float* bias = (z == 0) ? bq : (z == 1) ? bk : bv;
    const int m0 = blockIdx.x * 128, n0 = blockIdx.y * 128;
    const int t = threadIdx.x, wid = t >> 6, lane = t & 63;
    const int wr = wid >> 1, wc = wid & 1;

    f32x4 acc[4][4] = {};
    stage_tile(xb, DM, m0, 0, As[0], wid, lane);
    stage_tile(W,  DM, n0, 0, Bs[0], wid, lane);
    __syncthreads();
    int cur = 0;
    for (int kt = 0; kt < DM; kt += 32) {
        const int nxt = kt + 32;
        if (nxt < DM) {
            stage_tile(xb, DM, m0, nxt, As[cur ^ 1], wid, lane);
            stage_tile(W,  DM, n0, nxt, Bs[cur ^ 1], wid, lane);
        }
        frag_mma(As[cur], Bs[cur], wr, wc, lane, acc);
        __syncthreads();
        cur ^= 1;
    }

    const int lrow = lane & 15, lg = lane >> 4;
    if (z < 2) {
        u16* out = (z == 0) ? qb : kb;
        #pragma unroll
        for (int ni = 0; ni < 4; ++ni) {
            const int n = n0 + wc * 64 + ni * 16 + lrow;
            const float bn = bias[n];
            #pragma unroll
            for (int mi = 0; mi < 4; ++mi) {
                const int mb = m0 + wr * 64 + mi * 16 + lg * 4;
                #pragma unroll
                for (int r = 0; r < 4; ++r)
                    out[(size_t)(mb + r) * DM + n] = f2bf(acc[mi][ni][r] + bn);
            }
        }
    } else {
        #pragma unroll
        for (int ni = 0; ni < 4; ++ni) {
            const int n = n0 + wc * 64 + ni * 16 + lrow;
            const float bn = bias[n];
            #pragma unroll
            for (int mi = 0; mi < 4; ++mi) {
                const int mb = m0 + wr * 64 + mi * 16 + lg * 4;
                us4 p{f2bf(acc[mi][ni][0] + bn), f2bf(acc[mi][ni][1] + bn),
                      f2bf(acc[mi][ni][2] + bn), f2bf(acc[mi][ni][3] + bn)};
                *(us4*)(vT + (size_t)n * NTOK + mb) = p;   // transposed store
            }
        }
    }
}

// ---------------------------------------------------------------------------
// scores = q k^T / 32 (fp32 out), causal block skip (n0 > m0), double-buffered
// ---------------------------------------------------------------------------
__global__ __launch_bounds__(256) void qk_mfma(
    const u16* __restrict__ qb, const u16* __restrict__ kb,
    float* __restrict__ sc)
{
    const int m0 = blockIdx.x * 128, n0 = blockIdx.y * 128;
    if (n0 > m0) return;
    __shared__ u16 As[2][128 * 32], Bs[2][128 * 32];
    const int b = blockIdx.z;
    const u16* A = qb + (size_t)b * SEQ * DM;
    const u16* B = kb + (size_t)b * SEQ * DM;
    float* C = sc + (size_t)b * SEQ * SEQ;
    const int t = threadIdx.x, wid = t >> 6, lane = t & 63;
    const int wr = wid >> 1, wc = wid & 1;

    f32x4 acc[4][4] = {};
    stage_tile(A, DM, m0, 0, As[0], wid, lane);
    stage_tile(B, DM, n0, 0, Bs[0], wid, lane);
    __syncthreads();
    int cur = 0;
    for (int kt = 0; kt < DM; kt += 32) {
        const int nxt = kt + 32;
        if (nxt < DM) {
            stage_tile(A, DM, m0, nxt, As[cur ^ 1], wid, lane);
            stage_tile(B, DM, n0, nxt, Bs[cur ^ 1], wid, lane);
        }
        frag_mma(As[cur], Bs[cur], wr, wc, lane, acc);
        __syncthreads();
        cur ^= 1;
    }
    const int lrow = lane & 15, lg = lane >> 4;
    #pragma unroll
    for (int mi = 0; mi < 4; ++mi) {
        const int mb = m0 + wr * 64 + mi * 16 + lg * 4;
        #pragma unroll
        for (int ni = 0; ni < 4; ++ni) {
            const int n = n0 + wc * 64 + ni * 16 + lrow;
            #pragma unroll
            for (int r = 0; r < 4; ++r)
                C[(size_t)(mb + r) * SEQ + n] = acc[mi][ni][r] * 0.03125f;
        }
    }
}

// ---------------------------------------------------------------------------
// causal row softmax: one WAVE per row, row held entirely in registers
// (8 x float4 per lane = 2048 floats per wave). No LDS, no idle-lane tail.
// grid = BATCH*SEQ/4 blocks of 256 (4 waves = 4 rows per block).
// ---------------------------------------------------------------------------
__global__ __launch_bounds__(256) void softmax_rows(
    const float* __restrict__ sc, u16* __restrict__ attn)
{
    const int row  = blockIdx.x * 4 + (threadIdx.x >> 6);
    const int lane = threadIdx.x & 63;
    const int b = row >> 11, i = row & (SEQ - 1);
    const float* s = sc + (size_t)b * SEQ * SEQ + (size_t)i * SEQ;
    u16* a = attn + (size_t)b * SEQ * SEQ + (size_t)i * SEQ;

    const int nch = (i >> 8) + 1;          // chunks containing any j <= i
    float4 v[8];
    float lmax = -INFINITY;
    #pragma unroll
    for (int c = 0; c < 8; ++c) {
        if (c < nch) {
            v[c] = ((const float4*)s)[c * 64 + lane];
            const int j0 = c * 256 + lane * 4;
            if (j0 + 0 > i) v[c].x = -INFINITY;
            if (j0 + 1 > i) v[c].y = -INFINITY;
            if (j0 + 2 > i) v[c].z = -INFINITY;
            if (j0 + 3 > i) v[c].w = -INFINITY;
            lmax = fmaxf(lmax,
                   fmaxf(fmaxf(v[c].x, v[c].y), fmaxf(v[c].z, v[c].w)));
        }
    }
    #pragma unroll
    for (int o = 32; o > 0; o >>= 1) lmax = fmaxf(lmax, __shfl_xor(lmax, o));

    float lsum = 0.f;
    #pragma unroll
    for (int c = 0; c < 8; ++c) {
        if (c < nch) {
            v[c].x = __expf(v[c].x - lmax);   // exp(-inf - m) = 0 for masked
            v[c].y = __expf(v[c].y - lmax);
            v[c].z = __expf(v[c].z - lmax);
            v[c].w = __expf(v[c].w - lmax);
            lsum += (v[c].x + v[c].y) + (v[c].z + v[c].w);
        }
    }
    #pragma unroll
    for (int o = 32; o > 0; o >>= 1) lsum += __shfl_xor(lsum, o);
    const float inv = 1.f / lsum;

    #pragma unroll
    for (int c = 0; c < 8; ++c) {
        us4 p;
        if (c < nch) {
            p.x = f2bf(v[c].x * inv); p.y = f2bf(v[c].y * inv);
            p.z = f2bf(v[c].z * inv); p.w = f2bf(v[c].w * inv);
        } else {
            p.x = 0; p.y = 0; p.z = 0; p.w = 0;
        }
        ((us4*)a)[c * 64 + lane] = p;
    }
}

// ---------------------------------------------------------------------------
// out = attn @ v : NT GEMM vs vT[d][tok], causal K-limit, double-buffered
// ---------------------------------------------------------------------------
__global__ __launch_bounds__(256) void pv_mfma(
    const u16* __restrict__ attn, const u16* __restrict__ vT,
    float* __restrict__ out)
{
    __shared__ u16 As[2][128 * 32], Bs[2][128 * 32];
    const int m0 = blockIdx.x * 128, n0 = blockIdx.y * 128;
    const int b = blockIdx.z;
    const u16* A = attn + (size_t)b * SEQ * SEQ;   // lda = SEQ
    const u16* B = vT + (size_t)b * SEQ;           // ldb = NTOK, cols of batch b
    float* C = out + (size_t)b * SEQ * DM;
    const int t = threadIdx.x, wid = t >> 6, lane = t & 63;
    const int wr = wid >> 1, wc = wid & 1;

    f32x4 acc[4][4] = {};
    const int kmax = m0 + 128;   // causal: rows m0..m0+127 need k < m0+128
    stage_tile(A, SEQ,  m0, 0, As[0], wid, lane);
    stage_tile(B, NTOK, n0, 0, Bs[0], wid, lane);
    __syncthreads();
    int cur = 0;
    for (int kt = 0; kt < kmax; kt += 32) {
        const int nxt = kt + 32;
        if (nxt < kmax) {
            stage_tile(A, SEQ,  m0, nxt, As[cur ^ 1], wid, lane);
            stage_tile(B, NTOK, n0, nxt, Bs[cur ^ 1], wid, lane);
        }
        frag_mma(As[cur], Bs[cur], wr, wc, lane, acc);
        __syncthreads();
        cur ^= 1;
    }
    const int lrow = lane & 15, lg = lane >> 4;
    #pragma unroll
    for (int mi = 0; mi < 4; ++mi) {
        const int mb = m0 + wr * 64 + mi * 16 + lg * 4;
        #pragma unroll
        for (int ni = 0; ni < 4; ++ni) {
            const int n = n0 + wc * 64 + ni * 16 + lrow;
            #pragma unroll
            for (int r = 0; r < 4; ++r)
                C[(size_t)(mb + r) * DM + n] = acc[mi][ni][r];
        }
    }
}

// ---------------------------------------------------------------------------
extern "C" void kernel_launch(void* const* d_in, const int* in_sizes, int n_in,
                              void* d_out, int out_size, void* d_ws, size_t ws_size,
                              hipStream_t stream)
{
    const float* x  = (const float*)d_in[0];
    const float* wq = (const float*)d_in[1];
    const float* bq = (const float*)d_in[2];
    const float* wk = (const float*)d_in[3];
    const float* bk = (const float*)d_in[4];
    const float* wv = (const float*)d_in[5];
    const float* bv = (const float*)d_in[6];
    float* out = (float*)d_out;

    // ws layout (u16 elems): xb | wqb | wkb | wvb | qb | kb | vT | sc(f32) | attn
    u16* ws  = (u16*)d_ws;
    u16* xb  = ws;
    u16* wqb = xb  + (size_t)NTOK * DM;
    u16* wkb = wqb + (size_t)DM * DM;
    u16* wvb = wkb + (size_t)DM * DM;
    u16* qb  = wvb + (size_t)DM * DM;
    u16* kb  = qb  + (size_t)NTOK * DM;
    u16* vT  = kb  + (size_t)NTOK * DM;        // [DM][NTOK]
    float* sc = (float*)(vT + (size_t)NTOK * DM);
    u16* attn = (u16*)(sc + (size_t)BATCH * SEQ * SEQ);

    conv_bf16<<<2048, 256, 0, stream>>>(x, xb, NTOK * DM / 4);
    conv_bf16_w3<<<dim3(512, 1, 3), 256, 0, stream>>>(
        wq, wk, wv, wqb, wkb, wvb);

    qkv_mfma<<<dim3(NTOK / 128, DM / 128, 3), 256, 0, stream>>>(
        xb, wqb, bq, wkb, bk, wvb, bv, qb, kb, vT);

    qk_mfma<<<dim3(SEQ / 128, SEQ / 128, BATCH), 256, 0, stream>>>(qb, kb, sc);

    softmax_rows<<<BATCH * SEQ / 4, 256, 0, stream>>>(sc, attn);

    pv_mfma<<<dim3(SEQ / 128, DM / 128, BATCH), 256, 0, stream>>>(attn, vT, out);
}

// Round 8
// 201.658 us; speedup vs baseline: 1.0317x; 1.0317x over previous
//
#include <hip/hip_runtime.h>
#include <math.h>

#define BATCH 4
#define SEQ   2048
#define DM    1024
#define NTOK  (BATCH * SEQ)   // 8192

typedef __attribute__((ext_vector_type(8))) short bf16x8;
typedef __attribute__((ext_vector_type(4))) float f32x4;
typedef unsigned short u16;
struct alignas(8) us4 { u16 x, y, z, w; };

__device__ __forceinline__ u16 f2bf(float f) {
    union { float f; unsigned u; } v; v.f = f;
    unsigned r = v.u + 0x7fffu + ((v.u >> 16) & 1u);   // round-to-nearest-even
    return (u16)(r >> 16);
}

__device__ __forceinline__ void gload_lds16(const void* g, void* l) {
    __builtin_amdgcn_global_load_lds(
        (const __attribute__((address_space(1))) unsigned int*)g,
        (__attribute__((address_space(3))) unsigned int*)l, 16, 0, 0);
}

// Stage a 128-row x 32-k bf16 tile from row-major global (ld elems) into a
// linear LDS tile [128][32]. 4 waves x 2 issues x 64 lanes x 16B = 8192 B.
__device__ __forceinline__ void stage_tile(
    const u16* __restrict__ G, int ld, int row0, int kt,
    u16* lds, int wid, int lane)
{
    #pragma unroll
    for (int j = 0; j < 2; ++j) {
        const int off  = wid * 2048 + j * 1024;     // bytes, wave-uniform
        const int loff = off + lane * 16;           // this lane's dest byte
        const int row  = loff >> 6;                 // 64 B per row
        const int ke   = (loff & 63) >> 1;          // k-element offset
        gload_lds16(G + (size_t)(row0 + row) * ld + kt + ke, (char*)lds + off);
    }
}

// Per wave: 4x4 fragments of 16x16x32 over a 64x64 sub-tile (NT semantics).
// C/D: col=lane&15, row=(lane>>4)*4+r.
__device__ __forceinline__ void frag_mma(
    const u16* As, const u16* Bs, int wr, int wc, int lane, f32x4 acc[4][4])
{
    const int lrow = lane & 15, lk = (lane >> 4) * 8;
    bf16x8 a[4], b[4];
    #pragma unroll
    for (int i = 0; i < 4; ++i)
        a[i] = *(const bf16x8*)(As + (wr * 64 + i * 16 + lrow) * 32 + lk);
    #pragma unroll
    for (int i = 0; i < 4; ++i)
        b[i] = *(const bf16x8*)(Bs + (wc * 64 + i * 16 + lrow) * 32 + lk);
    #pragma unroll
    for (int i = 0; i < 4; ++i)
        #pragma unroll
        for (int j = 0; j < 4; ++j)
            acc[i][j] = __builtin_amdgcn_mfma_f32_16x16x32_bf16(
                a[i], b[j], acc[i][j], 0, 0, 0);
}

// ---------------------------------------------------------------------------
// f32 -> bf16 convert, float4 in / us4 out
// ---------------------------------------------------------------------------
__global__ __launch_bounds__(256) void conv_bf16(
    const float* __restrict__ in, u16* __restrict__ out, int n4)
{
    for (int i = blockIdx.x * 256 + threadIdx.x; i < n4; i += gridDim.x * 256) {
        float4 f = ((const float4*)in)[i];
        us4 p{f2bf(f.x), f2bf(f.y), f2bf(f.z), f2bf(f.w)};
        ((us4*)out)[i] = p;
    }
}

// 3 weight matrices in one launch (z selects)
__global__ __launch_bounds__(256) void conv_bf16_w3(
    const float* __restrict__ w0, const float* __restrict__ w1,
    const float* __restrict__ w2,
    u16* __restrict__ o0, u16* __restrict__ o1, u16* __restrict__ o2)
{
    const int z = blockIdx.z;
    const float* in = (z == 0) ? w0 : (z == 1) ? w1 : w2;
    u16* out = (z == 0) ? o0 : (z == 1) ? o1 : o2;
    const int n4 = DM * DM / 4;
    for (int i = blockIdx.x * 256 + threadIdx.x; i < n4; i += gridDim.x * 256) {
        float4 f = ((const float4*)in)[i];
        us4 p{f2bf(f.x), f2bf(f.y), f2bf(f.z), f2bf(f.w)};
        ((us4*)out)[i] = p;
    }
}

// ---------------------------------------------------------------------------
// QKV projection: NT GEMM  out[m][n] = sum_k x[m][k] W[n][k] + b[n]
// Single-buffer 2-barrier K-loop (measured-best structure, R4).
// z=0 -> q bf16 [NTOK][DM], z=1 -> k bf16, z=2 -> vT bf16 [DM][NTOK]
// ---------------------------------------------------------------------------
__global__ __launch_bounds__(256) void qkv_mfma(
    const u16* __restrict__ xb,
    const u16* __restrict__ wqb, const float* __restrict__ bq,
    const u16* __restrict__ wkb, const float* __restrict__ bk,
    const u16* __restrict__ wvb, const float* __restrict__ bv,
    u16* __restrict__ qb, u16* __restrict__ kb, u16* __restrict__ vT)
{
    __shared__ u16 As[128 * 32], Bs[128 * 32];
    const int z = blockIdx.z;
    const u16* W = (z == 0) ? wqb : (z == 1) ? wkb : wvb;
    const float* bias = (z == 0) ? bq : (z == 1) ? bk : bv;
    const int m0 = blockIdx.x * 128, n0 = blockIdx.y * 128;
    const int t = threadIdx.x, wid = t >> 6, lane = t & 63;
    const int wr = wid >> 1, wc = wid & 1;

    f32x4 acc[4][4] = {};
    for (int kt = 0; kt < DM; kt += 32) {
        __syncthreads();
        stage_tile(xb, DM, m0, kt, As, wid, lane);
        stage_tile(W,  DM, n0, kt, Bs, wid, lane);
        __syncthreads();
        frag_mma(As, Bs, wr, wc, lane, acc);
    }

    const int lrow = lane & 15, lg = lane >> 4;
    if (z < 2) {
        u16* out = (z == 0) ? qb : kb;
        #pragma unroll
        for (int ni = 0; ni < 4; ++ni) {
            const int n = n0 + wc * 64 + ni * 16 + lrow;
            const float bn = bias[n];
            #pragma unroll
            for (int mi = 0; mi < 4; ++mi) {
                const int mb = m0 + wr * 64 + mi * 16 + lg * 4;
                #pragma unroll
                for (int r = 0; r < 4; ++r)
                    out[(size_t)(mb + r) * DM + n] = f2bf(acc[mi][ni][r] + bn);
            }
        }
    } else {
        #pragma unroll
        for (int ni = 0; ni < 4; ++ni) {
            const int n = n0 + wc * 64 + ni * 16 + lrow;
            const float bn = bias[n];
            #pragma unroll
            for (int mi = 0; mi < 4; ++mi) {
                const int mb = m0 + wr * 64 + mi * 16 + lg * 4;
                us4 p{f2bf(acc[mi][ni][0] + bn), f2bf(acc[mi][ni][1] + bn),
                      f2bf(acc[mi][ni][2] + bn), f2bf(acc[mi][ni][3] + bn)};
                *(us4*)(vT + (size_t)n * NTOK + mb) = p;   // transposed store
            }
        }
    }
}

// ---------------------------------------------------------------------------
// Fused scores+exp: p = exp(q.k/32) masked causal, bf16 out (UNnormalized),
// plus per-row partial sums psum[b][row][nb] (nb = 64-col block index, 32/row).
// Normalization deferred to pv_mfma (softmax is shift-invariant; scores are
// bounded ~|s|<2 so exp without max-subtraction is fp32-safe).
// ---------------------------------------------------------------------------
__global__ __launch_bounds__(256) void qk_exp(
    const u16* __restrict__ qb, const u16* __restrict__ kb,
    u16* __restrict__ attn, float* __restrict__ psum)
{
    const int m0 = blockIdx.x * 128, n0 = blockIdx.y * 128;
    if (n0 > m0) return;                      // fully masked block
    __shared__ u16 As[128 * 32], Bs[128 * 32];
    const int b = blockIdx.z;
    const u16* A = qb + (size_t)b * SEQ * DM;
    const u16* B = kb + (size_t)b * SEQ * DM;
    u16* P = attn + (size_t)b * SEQ * SEQ;
    const int t = threadIdx.x, wid = t >> 6, lane = t & 63;
    const int wr = wid >> 1, wc = wid & 1;

    f32x4 acc[4][4] = {};
    for (int kt = 0; kt < DM; kt += 32) {
        __syncthreads();
        stage_tile(A, DM, m0, kt, As, wid, lane);
        stage_tile(B, DM, n0, kt, Bs, wid, lane);
        __syncthreads();
        frag_mma(As, Bs, wr, wc, lane, acc);
    }
    const int lrow = lane & 15, lg = lane >> 4;
    const float scale = 0.03125f;  // 1/sqrt(1024)
    const int nb = (n0 >> 6) | wc;
    #pragma unroll
    for (int mi = 0; mi < 4; ++mi) {
        #pragma unroll
        for (int r = 0; r < 4; ++r) {
            const int row = m0 + wr * 64 + mi * 16 + lg * 4 + r;
            float ps = 0.f;
            #pragma unroll
            for (int ni = 0; ni < 4; ++ni) {
                const int n = n0 + wc * 64 + ni * 16 + lrow;
                const float p = (n <= row) ? __expf(acc[mi][ni][r] * scale) : 0.f;
                P[(size_t)row * SEQ + n] = f2bf(p);
                ps += p;
            }
            // reduce over the 16 lanes (lrow) holding this row's 64 cols
            #pragma unroll
            for (int mk = 1; mk < 16; mk <<= 1) ps += __shfl_xor(ps, mk);
            if (lrow == 0)
                psum[((size_t)b * SEQ + row) * 32 + nb] = ps;
        }
    }
}

// ---------------------------------------------------------------------------
// out = (p @ v) / rowsum : NT GEMM vs vT[d][tok], causal K-limit.
// Prologue folds the <=32 psum partials per row into 1/rowsum (LDS).
// ---------------------------------------------------------------------------
__global__ __launch_bounds__(256) void pv_mfma(
    const u16* __restrict__ attn, const u16* __restrict__ vT,
    const float* __restrict__ psum, float* __restrict__ out)
{
    __shared__ u16 As[128 * 32], Bs[128 * 32];
    __shared__ float invs[128];
    const int m0 = blockIdx.x * 128, n0 = blockIdx.y * 128;
    const int b = blockIdx.z;
    const u16* A = attn + (size_t)b * SEQ * SEQ;   // lda = SEQ
    const u16* B = vT + (size_t)b * SEQ;           // ldb = NTOK, cols of batch b
    float* C = out + (size_t)b * SEQ * DM;
    const int t = threadIdx.x, wid = t >> 6, lane = t & 63;
    const int wr = wid >> 1, wc = wid & 1;

    if (t < 128) {
        const int row = m0 + t;
        const float* pr = psum + ((size_t)b * SEQ + row) * 32;
        const int nbmax = (row >> 6) | 1;      // all written blocks for this row
        float s = 0.f;
        for (int nbi = 0; nbi <= nbmax; ++nbi) s += pr[nbi];
        invs[t] = 1.f / s;
    }

    f32x4 acc[4][4] = {};
    const int kmax = m0 + 128;   // causal: rows m0..m0+127 need k < m0+128
    for (int kt = 0; kt < kmax; kt += 32) {
        __syncthreads();
        stage_tile(A, SEQ,  m0, kt, As, wid, lane);
        stage_tile(B, NTOK, n0, kt, Bs, wid, lane);
        __syncthreads();
        frag_mma(As, Bs, wr, wc, lane, acc);
    }
    const int lrow = lane & 15, lg = lane >> 4;
    #pragma unroll
    for (int mi = 0; mi < 4; ++mi) {
        const int ml = wr * 64 + mi * 16 + lg * 4;
        #pragma unroll
        for (int ni = 0; ni < 4; ++ni) {
            const int n = n0 + wc * 64 + ni * 16 + lrow;
            #pragma unroll
            for (int r = 0; r < 4; ++r)
                C[(size_t)(m0 + ml + r) * DM + n] = acc[mi][ni][r] * invs[ml + r];
        }
    }
}

// ---------------------------------------------------------------------------
extern "C" void kernel_launch(void* const* d_in, const int* in_sizes, int n_in,
                              void* d_out, int out_size, void* d_ws, size_t ws_size,
                              hipStream_t stream)
{
    const float* x  = (const float*)d_in[0];
    const float* wq = (const float*)d_in[1];
    const float* bq = (const float*)d_in[2];
    const float* wk = (const float*)d_in[3];
    const float* bk = (const float*)d_in[4];
    const float* wv = (const float*)d_in[5];
    const float* bv = (const float*)d_in[6];
    float* out = (float*)d_out;

    // ws layout (u16 elems): xb | wqb | wkb | wvb | qb | kb | vT | attn | psum
    u16* ws  = (u16*)d_ws;
    u16* xb  = ws;
    u16* wqb = xb  + (size_t)NTOK * DM;
    u16* wkb = wqb + (size_t)DM * DM;
    u16* wvb = wkb + (size_t)DM * DM;
    u16* qb  = wvb + (size_t)DM * DM;
    u16* kb  = qb  + (size_t)NTOK * DM;
    u16* vT  = kb  + (size_t)NTOK * DM;        // [DM][NTOK]
    u16* attn = vT + (size_t)NTOK * DM;        // bf16 [B][SEQ][SEQ], 32 MB
    float* psum = (float*)(attn + (size_t)BATCH * SEQ * SEQ);  // [B][SEQ][32]

    conv_bf16<<<2048, 256, 0, stream>>>(x, xb, NTOK * DM / 4);
    conv_bf16_w3<<<dim3(512, 1, 3), 256, 0, stream>>>(
        wq, wk, wv, wqb, wkb, wvb);

    qkv_mfma<<<dim3(NTOK / 128, DM / 128, 3), 256, 0, stream>>>(
        xb, wqb, bq, wkb, bk, wvb, bv, qb, kb, vT);

    qk_exp<<<dim3(SEQ / 128, SEQ / 128, BATCH), 256, 0, stream>>>(
        qb, kb, attn, psum);

    pv_mfma<<<dim3(SEQ / 128, DM / 128, BATCH), 256, 0, stream>>>(
        attn, vT, psum, out);
}

// Round 9
// 177.894 us; speedup vs baseline: 1.1695x; 1.1336x over previous
//
#include <hip/hip_runtime.h>
#include <math.h>

#define BATCH 4
#define SEQ   2048
#define DM    1024
#define NTOK  (BATCH * SEQ)   // 8192

typedef __attribute__((ext_vector_type(8))) short bf16x8;
typedef __attribute__((ext_vector_type(4))) float f32x4;
typedef unsigned short u16;
struct alignas(8) us4 { u16 x, y, z, w; };

__device__ __forceinline__ u16 f2bf(float f) {
    union { float f; unsigned u; } v; v.f = f;
    unsigned r = v.u + 0x7fffu + ((v.u >> 16) & 1u);   // round-to-nearest-even
    return (u16)(r >> 16);
}

__device__ __forceinline__ void gload_lds16(const void* g, void* l) {
    __builtin_amdgcn_global_load_lds(
        (const __attribute__((address_space(1))) unsigned int*)g,
        (__attribute__((address_space(3))) unsigned int*)l, 16, 0, 0);
}

// Stage a 128-row x 32-k bf16 tile from row-major global (ld elems) into a
// linear LDS tile [128][32]. 4 waves x 2 issues x 64 lanes x 16B = 8192 B.
__device__ __forceinline__ void stage_tile(
    const u16* __restrict__ G, int ld, int row0, int kt,
    u16* lds, int wid, int lane)
{
    #pragma unroll
    for (int j = 0; j < 2; ++j) {
        const int off  = wid * 2048 + j * 1024;     // bytes, wave-uniform
        const int loff = off + lane * 16;           // this lane's dest byte
        const int row  = loff >> 6;                 // 64 B per row
        const int ke   = (loff & 63) >> 1;          // k-element offset
        gload_lds16(G + (size_t)(row0 + row) * ld + kt + ke, (char*)lds + off);
    }
}

// Per wave: 4x4 fragments of 16x16x32 over a 64x64 sub-tile (NT semantics).
// C/D: col=lane&15, row=(lane>>4)*4+r.
__device__ __forceinline__ void frag_mma(
    const u16* As, const u16* Bs, int wr, int wc, int lane, f32x4 acc[4][4])
{
    const int lrow = lane & 15, lk = (lane >> 4) * 8;
    bf16x8 a[4], b[4];
    #pragma unroll
    for (int i = 0; i < 4; ++i)
        a[i] = *(const bf16x8*)(As + (wr * 64 + i * 16 + lrow) * 32 + lk);
    #pragma unroll
    for (int i = 0; i < 4; ++i)
        b[i] = *(const bf16x8*)(Bs + (wc * 64 + i * 16 + lrow) * 32 + lk);
    #pragma unroll
    for (int i = 0; i < 4; ++i)
        #pragma unroll
        for (int j = 0; j < 4; ++j)
            acc[i][j] = __builtin_amdgcn_mfma_f32_16x16x32_bf16(
                a[i], b[j], acc[i][j], 0, 0, 0);
}

// ---------------------------------------------------------------------------
// f32 -> bf16 convert, all four inputs in one launch.
// z=0: x (NTOK*DM), z=1..3: weights (DM*DM each).
// ---------------------------------------------------------------------------
__global__ __launch_bounds__(256) void conv_all(
    const float* __restrict__ x,
    const float* __restrict__ w0, const float* __restrict__ w1,
    const float* __restrict__ w2,
    u16* __restrict__ xo,
    u16* __restrict__ o0, u16* __restrict__ o1, u16* __restrict__ o2)
{
    const int z = blockIdx.z;
    const float* in = (z == 0) ? x : (z == 1) ? w0 : (z == 2) ? w1 : w2;
    u16* out = (z == 0) ? xo : (z == 1) ? o0 : (z == 2) ? o1 : o2;
    const int n4 = (z == 0) ? (NTOK * DM / 4) : (DM * DM / 4);
    for (int i = blockIdx.x * 256 + threadIdx.x; i < n4; i += gridDim.x * 256) {
        float4 f = ((const float4*)in)[i];
        us4 p{f2bf(f.x), f2bf(f.y), f2bf(f.z), f2bf(f.w)};
        ((us4*)out)[i] = p;
    }
}

// ---------------------------------------------------------------------------
// QKV projection: NT GEMM  out[m][n] = sum_k x[m][k] W[n][k] + b[n]
// Single-buffer 2-barrier K-loop. __launch_bounds__(256,3) forces the
// allocator to fit 3 waves/SIMD (combined VGPR+AGPR <= ~170): R8 measured
// 180 regs -> 2 waves/SIMD (21% occupancy); m97's overlap mechanism needs 3.
// z=0 -> q bf16 [NTOK][DM], z=1 -> k bf16, z=2 -> vT bf16 [DM][NTOK]
// ---------------------------------------------------------------------------
__global__ __launch_bounds__(256, 3) void qkv_mfma(
    const u16* __restrict__ xb,
    const u16* __restrict__ wqb, const float* __restrict__ bq,
    const u16* __restrict__ wkb, const float* __restrict__ bk,
    const u16* __restrict__ wvb, const float* __restrict__ bv,
    u16* __restrict__ qb, u16* __restrict__ kb, u16* __restrict__ vT)
{
    __shared__ u16 As[128 * 32], Bs[128 * 32];
    const int z = blockIdx.z;
    const u16* W = (z == 0) ? wqb : (z == 1) ? wkb : wvb;
    const float* bias = (z == 0) ? bq : (z == 1) ? bk : bv;
    const int m0 = blockIdx.x * 128, n0 = blockIdx.y * 128;
    const int t = threadIdx.x, wid = t >> 6, lane = t & 63;
    const int wr = wid >> 1, wc = wid & 1;

    f32x4 acc[4][4] = {};
    for (int kt = 0; kt < DM; kt += 32) {
        __syncthreads();
        stage_tile(xb, DM, m0, kt, As, wid, lane);
        stage_tile(W,  DM, n0, kt, Bs, wid, lane);
        __syncthreads();
        frag_mma(As, Bs, wr, wc, lane, acc);
    }

    const int lrow = lane & 15, lg = lane >> 4;
    if (z < 2) {
        u16* out = (z == 0) ? qb : kb;
        #pragma unroll
        for (int ni = 0; ni < 4; ++ni) {
            const int n = n0 + wc * 64 + ni * 16 + lrow;
            const float bn = bias[n];
            #pragma unroll
            for (int mi = 0; mi < 4; ++mi) {
                const int mb = m0 + wr * 64 + mi * 16 + lg * 4;
                #pragma unroll
                for (int r = 0; r < 4; ++r)
                    out[(size_t)(mb + r) * DM + n] = f2bf(acc[mi][ni][r] + bn);
            }
        }
    } else {
        #pragma unroll
        for (int ni = 0; ni < 4; ++ni) {
            const int n = n0 + wc * 64 + ni * 16 + lrow;
            const float bn = bias[n];
            #pragma unroll
            for (int mi = 0; mi < 4; ++mi) {
                const int mb = m0 + wr * 64 + mi * 16 + lg * 4;
                us4 p{f2bf(acc[mi][ni][0] + bn), f2bf(acc[mi][ni][1] + bn),
                      f2bf(acc[mi][ni][2] + bn), f2bf(acc[mi][ni][3] + bn)};
                *(us4*)(vT + (size_t)n * NTOK + mb) = p;   // transposed store
            }
        }
    }
}

// ---------------------------------------------------------------------------
// Fused scores+exp: p = exp(q.k/32) masked causal, bf16 out (UNnormalized),
// plus per-row partial sums psum[b][row][nb] (nb = 64-col block, 32/row).
// Normalization deferred to pv_mfma (softmax shift-invariant; |s|~<2).
// ---------------------------------------------------------------------------
__global__ __launch_bounds__(256, 3) void qk_exp(
    const u16* __restrict__ qb, const u16* __restrict__ kb,
    u16* __restrict__ attn, float* __restrict__ psum)
{
    const int m0 = blockIdx.x * 128, n0 = blockIdx.y * 128;
    if (n0 > m0) return;                      // fully masked block
    __shared__ u16 As[128 * 32], Bs[128 * 32];
    const int b = blockIdx.z;
    const u16* A = qb + (size_t)b * SEQ * DM;
    const u16* B = kb + (size_t)b * SEQ * DM;
    u16* P = attn + (size_t)b * SEQ * SEQ;
    const int t = threadIdx.x, wid = t >> 6, lane = t & 63;
    const int wr = wid >> 1, wc = wid & 1;

    f32x4 acc[4][4] = {};
    for (int kt = 0; kt < DM; kt += 32) {
        __syncthreads();
        stage_tile(A, DM, m0, kt, As, wid, lane);
        stage_tile(B, DM, n0, kt, Bs, wid, lane);
        __syncthreads();
        frag_mma(As, Bs, wr, wc, lane, acc);
    }
    const int lrow = lane & 15, lg = lane >> 4;
    const float scale = 0.03125f;  // 1/sqrt(1024)
    const int nb = (n0 >> 6) | wc;
    #pragma unroll
    for (int mi = 0; mi < 4; ++mi) {
        #pragma unroll
        for (int r = 0; r < 4; ++r) {
            const int row = m0 + wr * 64 + mi * 16 + lg * 4 + r;
            float ps = 0.f;
            #pragma unroll
            for (int ni = 0; ni < 4; ++ni) {
                const int n = n0 + wc * 64 + ni * 16 + lrow;
                const float p = (n <= row) ? __expf(acc[mi][ni][r] * scale) : 0.f;
                P[(size_t)row * SEQ + n] = f2bf(p);
                ps += p;
            }
            // reduce over the 16 lanes (lrow) holding this row's 64 cols
            #pragma unroll
            for (int mk = 1; mk < 16; mk <<= 1) ps += __shfl_xor(ps, mk);
            if (lrow == 0)
                psum[((size_t)b * SEQ + row) * 32 + nb] = ps;
        }
    }
}

// ---------------------------------------------------------------------------
// out = (p @ v) / rowsum : NT GEMM vs vT[d][tok], causal K-limit.
// Prologue folds the <=32 psum partials per row into 1/rowsum (LDS).
// ---------------------------------------------------------------------------
__global__ __launch_bounds__(256, 3) void pv_mfma(
    const u16* __restrict__ attn, const u16* __restrict__ vT,
    const float* __restrict__ psum, float* __restrict__ out)
{
    __shared__ u16 As[128 * 32], Bs[128 * 32];
    __shared__ float invs[128];
    const int m0 = blockIdx.x * 128, n0 = blockIdx.y * 128;
    const int b = blockIdx.z;
    const u16* A = attn + (size_t)b * SEQ * SEQ;   // lda = SEQ
    const u16* B = vT + (size_t)b * SEQ;           // ldb = NTOK, cols of batch b
    float* C = out + (size_t)b * SEQ * DM;
    const int t = threadIdx.x, wid = t >> 6, lane = t & 63;
    const int wr = wid >> 1, wc = wid & 1;

    if (t < 128) {
        const int row = m0 + t;
        const float* pr = psum + ((size_t)b * SEQ + row) * 32;
        const int nbmax = (row >> 6) | 1;      // all written blocks for this row
        float s = 0.f;
        for (int nbi = 0; nbi <= nbmax; ++nbi) s += pr[nbi];
        invs[t] = 1.f / s;
    }

    f32x4 acc[4][4] = {};
    const int kmax = m0 + 128;   // causal: rows m0..m0+127 need k < m0+128
    for (int kt = 0; kt < kmax; kt += 32) {
        __syncthreads();
        stage_tile(A, SEQ,  m0, kt, As, wid, lane);
        stage_tile(B, NTOK, n0, kt, Bs, wid, lane);
        __syncthreads();
        frag_mma(As, Bs, wr, wc, lane, acc);
    }
    const int lrow = lane & 15, lg = lane >> 4;
    #pragma unroll
    for (int mi = 0; mi < 4; ++mi) {
        const int ml = wr * 64 + mi * 16 + lg * 4;
        #pragma unroll
        for (int ni = 0; ni < 4; ++ni) {
            const int n = n0 + wc * 64 + ni * 16 + lrow;
            #pragma unroll
            for (int r = 0; r < 4; ++r)
                C[(size_t)(m0 + ml + r) * DM + n] = acc[mi][ni][r] * invs[ml + r];
        }
    }
}

// ---------------------------------------------------------------------------
extern "C" void kernel_launch(void* const* d_in, const int* in_sizes, int n_in,
                              void* d_out, int out_size, void* d_ws, size_t ws_size,
                              hipStream_t stream)
{
    const float* x  = (const float*)d_in[0];
    const float* wq = (const float*)d_in[1];
    const float* bq = (const float*)d_in[2];
    const float* wk = (const float*)d_in[3];
    const float* bk = (const float*)d_in[4];
    const float* wv = (const float*)d_in[5];
    const float* bv = (const float*)d_in[6];
    float* out = (float*)d_out;

    // ws layout (u16 elems): xb | wqb | wkb | wvb | qb | kb | vT | attn | psum
    u16* ws  = (u16*)d_ws;
    u16* xb  = ws;
    u16* wqb = xb  + (size_t)NTOK * DM;
    u16* wkb = wqb + (size_t)DM * DM;
    u16* wvb = wkb + (size_t)DM * DM;
    u16* qb  = wvb + (size_t)DM * DM;
    u16* kb  = qb  + (size_t)NTOK * DM;
    u16* vT  = kb  + (size_t)NTOK * DM;        // [DM][NTOK]
    u16* attn = vT + (size_t)NTOK * DM;        // bf16 [B][SEQ][SEQ], 32 MB
    float* psum = (float*)(attn + (size_t)BATCH * SEQ * SEQ);  // [B][SEQ][32]

    conv_all<<<dim3(512, 1, 4), 256, 0, stream>>>(
        x, wq, wk, wv, xb, wqb, wkb, wvb);

    qkv_mfma<<<dim3(NTOK / 128, DM / 128, 3), 256, 0, stream>>>(
        xb, wqb, bq, wkb, bk, wvb, bv, qb, kb, vT);

    qk_exp<<<dim3(SEQ / 128, SEQ / 128, BATCH), 256, 0, stream>>>(
        qb, kb, attn, psum);

    pv_mfma<<<dim3(SEQ / 128, DM / 128, BATCH), 256, 0, stream>>>(
        attn, vT, psum, out);
}